// Round 10
// baseline (1458.208 us; speedup 1.0000x reference)
//
#include <hip/hip_runtime.h>
#include <hip/hip_bf16.h>

#define M_DIM 8192
#define K_DIM 4096
#define N4    8192
#define N8    2816
#define NT    11008   // 43 * 256
#define TM    (M_DIM / 256)   // 32
#define TN    (NT / 256)      // 43
#define NKT   (K_DIM / 64)    // 64 K-tiles
#define NFULL 1280            // 5 * 256 full-tile blocks
#define GRID  1472            // 1280 full + 192 half (96 tiles split in M)

typedef __attribute__((ext_vector_type(4))) float  f32x4;
typedef __attribute__((ext_vector_type(4))) float  float4v;
typedef __attribute__((ext_vector_type(8))) __bf16 bf16x8;
typedef __attribute__((ext_vector_type(4))) unsigned short ushort4v;
typedef __attribute__((ext_vector_type(8))) unsigned short ushort8v;

__device__ __forceinline__ unsigned short f2bf(float f) {
  union { float f; unsigned int u; } v; v.f = f;
  unsigned int u = v.u;
  unsigned int r = u + 0x7FFFu + ((u >> 16) & 1u);   // RNE
  return (unsigned short)(r >> 16);
}

// ---- x fp32 -> bf16, contiguous ----
__global__ void conv_x_kernel(const float* __restrict__ x,
                              unsigned short* __restrict__ xb, int n8) {
  int idx = blockIdx.x * blockDim.x + threadIdx.x;
  int stride = gridDim.x * blockDim.x;
  for (int i = idx; i < n8; i += stride) {
    const float4v* src = (const float4v*)(x + (size_t)i * 8);
    float4v a = src[0], b = src[1];
    ushort8v o;
    o[0] = f2bf(a[0]); o[1] = f2bf(a[1]); o[2] = f2bf(a[2]); o[3] = f2bf(a[3]);
    o[4] = f2bf(b[0]); o[5] = f2bf(b[1]); o[6] = f2bf(b[2]); o[7] = f2bf(b[3]);
    ((ushort8v*)xb)[i] = o;
  }
}

// ---- gather W_cat[inv_perm[j]] row, fp32 -> bf16 (inv_perm is int32) ----
__global__ void conv_w_kernel(const float* __restrict__ w4,
                              const float* __restrict__ w8,
                              const int* __restrict__ inv_perm,
                              unsigned short* __restrict__ wb) {
  int j = blockIdx.x;
  int c = inv_perm[j];
  const float* src = (c < N4) ? (w4 + (size_t)c * K_DIM)
                              : (w8 + (size_t)(c - N4) * K_DIM);
  unsigned short* dst = wb + (size_t)j * K_DIM;
  int t = threadIdx.x;
#pragma unroll
  for (int it = 0; it < 4; ++it) {
    int e = it * 1024 + t * 4;
    float4v a = *(const float4v*)(src + e);
    ushort4v o;
    o[0] = f2bf(a[0]); o[1] = f2bf(a[1]); o[2] = f2bf(a[2]); o[3] = f2bf(a[3]);
    *(ushort4v*)(dst + e) = o;
  }
}

// ================= 256x256 8-phase bf16 GEMM (T1+T2+T3+T4+T5) =================
// Full tiles: register-pipelined fragment reads (issued one phase EARLY so the
// DS engine drains under MFMA). Read distribution 4/8/0/12 per K-tile.
// vmcnt/lgkm ledger (stages: ph1 A13(u+1); ph2 A02(u+2); ph3 B01(u+2); ph4 B23(u+2)):
//   ph1: vmcnt(8)  -> A13(u) landed   (protects ph2's a1 reads)   + lgkm(4)
//   ph2: lgkm(8)
//   ph3: vmcnt(6)  -> A02/B01/B23(u+1) landed (protects ph4's a0'/b0' reads) + lgkm(0)
//   ph4: lgkm(12)
// Blocks >= NFULL: half tiles (128x256) of the last 96 tiles -> tail flatten.
__global__ __launch_bounds__(512, 2)
void gemm256_kernel(const unsigned short* __restrict__ A,
                    const unsigned short* __restrict__ B,
                    const float* __restrict__ bias,
                    float* __restrict__ C) {
  __shared__ __align__(16) unsigned short lds[4 * 16384];  // 128 KiB

  int bid = blockIdx.x;
  int vbid, mhalf, is_half;
  if (bid < NFULL) { vbid = bid; mhalf = 0; is_half = 0; }
  else { int h = bid - NFULL; vbid = NFULL + (h >> 1); mhalf = h & 1; is_half = 1; }
  int wgid = (vbid & 7) * ((TM * TN) / 8) + (vbid >> 3);  // 1376 % 8 == 0, bijective
  int tile_m = wgid / TN;
  int tile_n = wgid % TN;

  const int tid  = threadIdx.x;
  const int wid  = tid >> 6;
  const int lane = tid & 63;
  const int wr  = wid >> 2;         // 0..1
  const int wcn = wid & 3;          // 0..3 (B quarter)
  const int l15 = lane & 15;
  // ds_read per-lane column byte offsets (swizzle folded in; row&7 == lane&7 for 16-aligned bases)
  const int rswz  = (lane & 7) << 4;
  const int coff0 = (((lane >> 4) * 16) + 0)  ^ rswz;   // kk=0
  const int coff1 = (((lane >> 4) * 16) + 64) ^ rswz;   // kk=1
  // stage per-lane source permutation: row_in_8 = lane>>3; (row&7)<<4 == (lane&0x38)<<1
  const int st_row8 = lane >> 3;
  const int st_scol = ((lane & 7) * 16) ^ ((lane & 0x38) << 1);  // bytes, < 128

  const size_t brow0 = (size_t)tile_n * 256;

  // stage one 64-row unit (8 KiB): wave wid covers rows [q*64+wid*8, +8)
  auto stage = [&](const unsigned short* __restrict__ g, size_t grow0,
                   unsigned short* ltile, int q, int ktelem) {
    int row = q * 64 + wid * 8 + st_row8;
    const unsigned short* src =
        g + (grow0 + (size_t)row) * K_DIM + ktelem + (st_scol >> 1);
    unsigned short* dst = ltile + (q * 64 + wid * 8) * 64;  // wave-uniform, linear
    __builtin_amdgcn_global_load_lds(
        (const __attribute__((address_space(1))) void*)src,
        (__attribute__((address_space(3))) void*)dst, 16, 0, 0);
  };
  auto fragld = [&](const unsigned short* ltile, int row, int coff) -> bf16x8 {
    return *(const bf16x8*)((const char*)ltile + row * 128 + coff);
  };

  if (is_half) {
    // ================== half-tile path (128x256), 3.5% of work ==============
    const size_t arowh = (size_t)tile_m * 256 + (size_t)mhalf * 128;
    f32x4 acch[4][4];
#pragma unroll
    for (int i = 0; i < 4; ++i)
#pragma unroll
      for (int j = 0; j < 4; ++j) acch[i][j] = (f32x4){0.f, 0.f, 0.f, 0.f};

    // prologue: tile0 -> buf0 (A 2 units, B 4 units)
    stage(A, arowh, lds + 0, 0, 0);      stage(A, arowh, lds + 0, 1, 0);
    stage(B, brow0, lds + 16384, 0, 0);  stage(B, brow0, lds + 16384, 1, 0);
    stage(B, brow0, lds + 16384, 2, 0);  stage(B, brow0, lds + 16384, 3, 0);
    asm volatile("s_waitcnt vmcnt(0)" ::: "memory");
    __builtin_amdgcn_s_barrier();

#pragma unroll 1
    for (int u = 0; u < NKT; ++u) {
      unsigned short* Ac = lds + (u & 1) * 32768;
      unsigned short* Bc = Ac + 16384;
      unsigned short* An = lds + (32768 - (u & 1) * 32768);
      if (u + 1 < NKT) {   // prefetch issued first; drained at iter end (latency hidden)
        int kn = (u + 1) * 64;
        stage(A, arowh, An, 0, kn);      stage(A, arowh, An, 1, kn);
        stage(B, brow0, An + 16384, 0, kn); stage(B, brow0, An + 16384, 1, kn);
        stage(B, brow0, An + 16384, 2, kn); stage(B, brow0, An + 16384, 3, kn);
      }
      bf16x8 ah[4][2], bh[4][2];
#pragma unroll
      for (int m = 0; m < 4; ++m) {
        int row = wr * 64 + m * 16 + l15;
        ah[m][0] = fragld(Ac, row, coff0);
        ah[m][1] = fragld(Ac, row, coff1);
      }
#pragma unroll
      for (int n = 0; n < 4; ++n) {
        int row = wcn * 64 + n * 16 + l15;
        bh[n][0] = fragld(Bc, row, coff0);
        bh[n][1] = fragld(Bc, row, coff1);
      }
      asm volatile("s_waitcnt lgkmcnt(0)" ::: "memory");
      __builtin_amdgcn_sched_barrier(0);
      __builtin_amdgcn_s_setprio(1);
#pragma unroll
      for (int m = 0; m < 4; ++m)
#pragma unroll
        for (int n = 0; n < 4; ++n) {
          acch[m][n] = __builtin_amdgcn_mfma_f32_16x16x32_bf16(ah[m][0], bh[n][0], acch[m][n], 0, 0, 0);
          acch[m][n] = __builtin_amdgcn_mfma_f32_16x16x32_bf16(ah[m][1], bh[n][1], acch[m][n], 0, 0, 0);
        }
      __builtin_amdgcn_s_setprio(0);
      asm volatile("s_waitcnt vmcnt(0)" ::: "memory");
      __builtin_amdgcn_s_barrier();
    }

#pragma unroll
    for (int n = 0; n < 4; ++n) {
      int col = tile_n * 256 + wcn * 64 + n * 16 + l15;
      float bv = bias[col];
#pragma unroll
      for (int m = 0; m < 4; ++m) {
        int row0 = tile_m * 256 + mhalf * 128 + wr * 64 + m * 16 + ((lane >> 4) * 4);
#pragma unroll
        for (int r = 0; r < 4; ++r) {
          C[(size_t)(row0 + r) * NT + col] = acch[m][n][r] + bv;
        }
      }
    }
    return;
  }

  // ====================== full-tile path (pipelined reads) ==================
  const size_t arow0 = (size_t)tile_m * 256;

  f32x4 acc[8][4];
#pragma unroll
  for (int i = 0; i < 8; ++i)
#pragma unroll
    for (int j = 0; j < 4; ++j) acc[i][j] = (f32x4){0.f, 0.f, 0.f, 0.f};

  bf16x8 a0[4][2], b0[2][2];   // loop-carried: read one phase early (ph4 of prev iter)

  // buffer layout (elements): buf0 A @0, B @16384; buf1 A @32768, B @49152

  // ---- prologue: tile0 full (8 units), tile1 A02+B01+B23 (6); tile1's A13 staged in u=0 ph1
  stage(A, arow0, lds + 0,     0, 0);  stage(A, arow0, lds + 0,     2, 0);
  stage(A, arow0, lds + 0,     1, 0);  stage(A, arow0, lds + 0,     3, 0);
  stage(B, brow0, lds + 16384, 0, 0);  stage(B, brow0, lds + 16384, 1, 0);
  stage(B, brow0, lds + 16384, 2, 0);  stage(B, brow0, lds + 16384, 3, 0);
  stage(A, arow0, lds + 32768, 0, 64); stage(A, arow0, lds + 32768, 2, 64);
  stage(B, brow0, lds + 49152, 0, 64); stage(B, brow0, lds + 49152, 1, 64);
  stage(B, brow0, lds + 49152, 2, 64); stage(B, brow0, lds + 49152, 3, 64);
  asm volatile("s_waitcnt vmcnt(6)" ::: "memory");  // tile0 (oldest 8 of 14) landed
  __builtin_amdgcn_s_barrier();

  // pre-read a0 + B0 of tile0 (feeds ph1(0) MFMA)
#pragma unroll
  for (int m = 0; m < 4; ++m) {
    int row = wr * 128 + m * 16 + l15;
    a0[m][0] = fragld(lds + 0, row, coff0);
    a0[m][1] = fragld(lds + 0, row, coff1);
  }
#pragma unroll
  for (int n = 0; n < 2; ++n) {
    int row = wcn * 64 + n * 16 + l15;
    b0[n][0] = fragld(lds + 16384, row, coff0);
    b0[n][1] = fragld(lds + 16384, row, coff1);
  }

#define KITER(AC, BC, AN, UN1, UN2)                                           \
  {                                                                           \
    unsigned short* const Ac = (AC);                                          \
    unsigned short* const Bc = (BC);                                          \
    unsigned short* const An = (AN);                                          \
    const int un1 = (UN1);                                                    \
    const int un2 = (UN2);                                                    \
    bf16x8 a1[4][2], b1[2][2];                                                \
    /* ph1: read b1(u) [4]; stage A13(u+1)->An; vmcnt(8)+lgkm(4); mfma m0 x n0 */ \
    _Pragma("unroll")                                                         \
    for (int n = 0; n < 2; ++n) {                                             \
      int row = wcn * 64 + (2 + n) * 16 + l15;                                \
      b1[n][0] = fragld(Bc, row, coff0);                                      \
      b1[n][1] = fragld(Bc, row, coff1);                                      \
    }                                                                         \
    stage(A, arow0, An, 1, un1);                                              \
    stage(A, arow0, An, 3, un1);                                              \
    __builtin_amdgcn_s_barrier();                                             \
    asm volatile("s_waitcnt vmcnt(8) lgkmcnt(4)" ::: "memory");               \
    __builtin_amdgcn_sched_barrier(0);                                        \
    __builtin_amdgcn_s_setprio(1);                                            \
    _Pragma("unroll")                                                         \
    for (int m = 0; m < 4; ++m)                                               \
      _Pragma("unroll")                                                       \
      for (int n = 0; n < 2; ++n) {                                           \
        acc[m][n] = __builtin_amdgcn_mfma_f32_16x16x32_bf16(a0[m][0], b0[n][0], acc[m][n], 0, 0, 0); \
        acc[m][n] = __builtin_amdgcn_mfma_f32_16x16x32_bf16(a0[m][1], b0[n][1], acc[m][n], 0, 0, 0); \
      }                                                                       \
    __builtin_amdgcn_s_setprio(0);                                            \
    __builtin_amdgcn_s_barrier();                                             \
    /* ph2: read a1(u) [8]; stage A02(u+2)->Ac; lgkm(8); mfma m0 x n1 */      \
    _Pragma("unroll")                                                         \
    for (int m = 0; m < 4; ++m) {                                             \
      int row = wr * 128 + 64 + m * 16 + l15;                                 \
      a1[m][0] = fragld(Ac, row, coff0);                                      \
      a1[m][1] = fragld(Ac, row, coff1);                                      \
    }                                                                         \
    stage(A, arow0, Ac, 0, un2);                                              \
    stage(A, arow0, Ac, 2, un2);                                              \
    __builtin_amdgcn_s_barrier();                                             \
    asm volatile("s_waitcnt lgkmcnt(8)" ::: "memory");                        \
    __builtin_amdgcn_sched_barrier(0);                                        \
    __builtin_amdgcn_s_setprio(1);                                            \
    _Pragma("unroll")                                                         \
    for (int m = 0; m < 4; ++m)                                               \
      _Pragma("unroll")                                                       \
      for (int n = 0; n < 2; ++n) {                                           \
        acc[m][2 + n] = __builtin_amdgcn_mfma_f32_16x16x32_bf16(a0[m][0], b1[n][0], acc[m][2 + n], 0, 0, 0); \
        acc[m][2 + n] = __builtin_amdgcn_mfma_f32_16x16x32_bf16(a0[m][1], b1[n][1], acc[m][2 + n], 0, 0, 0); \
      }                                                                       \
    __builtin_amdgcn_s_setprio(0);                                            \
    __builtin_amdgcn_s_barrier();                                             \
    /* ph3: no reads; stage B01(u+2)->Bc; vmcnt(6)+lgkm(0); mfma m1 x n0 */   \
    stage(B, brow0, Bc, 0, un2);                                              \
    stage(B, brow0, Bc, 1, un2);                                              \
    __builtin_amdgcn_s_barrier();                                             \
    asm volatile("s_waitcnt vmcnt(6) lgkmcnt(0)" ::: "memory");               \
    __builtin_amdgcn_sched_barrier(0);                                        \
    __builtin_amdgcn_s_setprio(1);                                            \
    _Pragma("unroll")                                                         \
    for (int m = 0; m < 4; ++m)                                               \
      _Pragma("unroll")                                                       \
      for (int n = 0; n < 2; ++n) {                                           \
        acc[4 + m][n] = __builtin_amdgcn_mfma_f32_16x16x32_bf16(a1[m][0], b0[n][0], acc[4 + m][n], 0, 0, 0); \
        acc[4 + m][n] = __builtin_amdgcn_mfma_f32_16x16x32_bf16(a1[m][1], b0[n][1], acc[4 + m][n], 0, 0, 0); \
      }                                                                       \
    __builtin_amdgcn_s_setprio(0);                                            \
    __builtin_amdgcn_s_barrier();                                             \
    /* ph4: read a0(u+1) [8] + b0(u+1) [4] from An (landed per ph3 vmcnt(6)); \
       stage B23(u+2)->Bc; lgkm(12); mfma m1 x n1 */                          \
    _Pragma("unroll")                                                         \
    for (int m = 0; m < 4; ++m) {                                             \
      int row = wr * 128 + m * 16 + l15;                                      \
      a0[m][0] = fragld(An, row, coff0);                                      \
      a0[m][1] = fragld(An, row, coff1);                                      \
    }                                                                         \
    _Pragma("unroll")                                                         \
    for (int n = 0; n < 2; ++n) {                                             \
      int row = wcn * 64 + n * 16 + l15;                                      \
      b0[n][0] = fragld(An + 16384, row, coff0);                              \
      b0[n][1] = fragld(An + 16384, row, coff1);                              \
    }                                                                         \
    stage(B, brow0, Bc, 2, un2);                                              \
    stage(B, brow0, Bc, 3, un2);                                              \
    __builtin_amdgcn_s_barrier();                                             \
    asm volatile("s_waitcnt lgkmcnt(12)" ::: "memory");                       \
    __builtin_amdgcn_sched_barrier(0);                                        \
    __builtin_amdgcn_s_setprio(1);                                            \
    _Pragma("unroll")                                                         \
    for (int m = 0; m < 4; ++m)                                               \
      _Pragma("unroll")                                                       \
      for (int n = 0; n < 2; ++n) {                                           \
        acc[4 + m][2 + n] = __builtin_amdgcn_mfma_f32_16x16x32_bf16(a1[m][0], b1[n][0], acc[4 + m][2 + n], 0, 0, 0); \
        acc[4 + m][2 + n] = __builtin_amdgcn_mfma_f32_16x16x32_bf16(a1[m][1], b1[n][1], acc[4 + m][2 + n], 0, 0, 0); \
      }                                                                       \
    __builtin_amdgcn_s_setprio(0);                                            \
    __builtin_amdgcn_s_barrier();                                             \
  }

#pragma unroll 1
  for (int u = 0; u < NKT; u += 2) {
    const int k1 = ((u + 1 < NKT) ? (u + 1) : (NKT - 1)) * 64;
    const int k2 = ((u + 2 < NKT) ? (u + 2) : (NKT - 1)) * 64;
    const int k3 = ((u + 3 < NKT) ? (u + 3) : (NKT - 1)) * 64;
    // even iter: buf0 current, buf1 next
    KITER(lds + 0,     lds + 16384, lds + 32768, k1, k2);
    // odd iter: buf1 current, buf0 next
    KITER(lds + 32768, lds + 49152, lds + 0,     k2, k3);
  }
#undef KITER

  // ---- epilogue: C/D layout col=lane&15, row=(lane>>4)*4+r
#pragma unroll
  for (int n = 0; n < 4; ++n) {
    int col = tile_n * 256 + wcn * 64 + n * 16 + l15;
    float bv = bias[col];
#pragma unroll
    for (int m = 0; m < 8; ++m) {
      int row0 = tile_m * 256 + wr * 128 + m * 16 + ((lane >> 4) * 4);
#pragma unroll
      for (int r = 0; r < 4; ++r) {
        C[(size_t)(row0 + r) * NT + col] = acc[m][n][r] + bv;
      }
    }
  }
}

// ============ fallback path: no workspace, fp32 sources, reg convert ========
__global__ void gemm_fused_f32_kernel(const float* __restrict__ x,
                                      const float* __restrict__ w4,
                                      const float* __restrict__ w8,
                                      const int* __restrict__ inv_perm,
                                      const float* __restrict__ bias,
                                      float* __restrict__ C) {
  __shared__ __align__(16) unsigned short Alds[128 * 64];
  __shared__ __align__(16) unsigned short Blds[128 * 64];

  int bid = blockIdx.x;
  int wgid = (bid & 7) * ((M_DIM / 128) * (NT / 128) / 8) + (bid >> 3);
  int tile_n = wgid % (NT / 128);
  int tile_m = wgid / (NT / 128);

  const int tid  = threadIdx.x;
  const int wid  = tid >> 6;
  const int lane = tid & 63;
  const int wr = wid >> 1, wc = wid & 1;

  f32x4 acc[4][4];
#pragma unroll
  for (int i = 0; i < 4; ++i)
#pragma unroll
    for (int j = 0; j < 4; ++j) acc[i][j] = (f32x4){0.f, 0.f, 0.f, 0.f};

  const int lrow = lane >> 3;
  const int lcol = (lane & 7) * 8;

  const float* asrc[4];
  const float* bsrc[4];
  int ldsoff[4];
#pragma unroll
  for (int s = 0; s < 4; ++s) {
    int rb = s * 32 + wid * 8 + lrow;
    asrc[s] = x + (size_t)(tile_m * 128 + rb) * K_DIM + lcol;
    int c = inv_perm[tile_n * 128 + rb];
    bsrc[s] = ((c < N4) ? (w4 + (size_t)c * K_DIM)
                        : (w8 + (size_t)(c - N4) * K_DIM)) + lcol;
    ldsoff[s] = rb * 64 + lcol;
  }

  for (int kt = 0; kt < K_DIM; kt += 64) {
#pragma unroll
    for (int s = 0; s < 4; ++s) {
      float4v a0 = *(const float4v*)(asrc[s] + kt);
      float4v a1 = *(const float4v*)(asrc[s] + kt + 4);
      float4v b0 = *(const float4v*)(bsrc[s] + kt);
      float4v b1 = *(const float4v*)(bsrc[s] + kt + 4);
      ushort8v oa, ob;
      oa[0]=f2bf(a0[0]); oa[1]=f2bf(a0[1]); oa[2]=f2bf(a0[2]); oa[3]=f2bf(a0[3]);
      oa[4]=f2bf(a1[0]); oa[5]=f2bf(a1[1]); oa[6]=f2bf(a1[2]); oa[7]=f2bf(a1[3]);
      ob[0]=f2bf(b0[0]); ob[1]=f2bf(b0[1]); ob[2]=f2bf(b0[2]); ob[3]=f2bf(b0[3]);
      ob[4]=f2bf(b1[0]); ob[5]=f2bf(b1[1]); ob[6]=f2bf(b1[2]); ob[7]=f2bf(b1[3]);
      *(ushort8v*)&Alds[ldsoff[s]] = oa;
      *(ushort8v*)&Blds[ldsoff[s]] = ob;
    }
    __syncthreads();

#pragma unroll
    for (int kk = 0; kk < 2; ++kk) {
      bf16x8 af[4], bfr[4];
#pragma unroll
      for (int i = 0; i < 4; ++i) {
        int row = wr * 64 + i * 16 + (lane & 15);
        af[i] = *(const bf16x8*)&Alds[row * 64 + kk * 32 + (lane >> 4) * 8];
      }
#pragma unroll
      for (int j = 0; j < 4; ++j) {
        int row = wc * 64 + j * 16 + (lane & 15);
        bfr[j] = *(const bf16x8*)&Blds[row * 64 + kk * 32 + (lane >> 4) * 8];
      }
#pragma unroll
      for (int i = 0; i < 4; ++i)
#pragma unroll
        for (int j = 0; j < 4; ++j)
          acc[i][j] = __builtin_amdgcn_mfma_f32_16x16x32_bf16(af[i], bfr[j], acc[i][j], 0, 0, 0);
    }
    __syncthreads();
  }

#pragma unroll
  for (int j = 0; j < 4; ++j) {
    int col = tile_n * 128 + wc * 64 + j * 16 + (lane & 15);
    float bv = bias[col];
#pragma unroll
    for (int i = 0; i < 4; ++i) {
      int row0 = tile_m * 128 + wr * 64 + i * 16 + ((lane >> 4) * 4);
#pragma unroll
      for (int r = 0; r < 4; ++r) {
        C[(size_t)(row0 + r) * NT + col] = acc[i][j][r] + bv;
      }
    }
  }
}

extern "C" void kernel_launch(void* const* d_in, const int* in_sizes, int n_in,
                              void* d_out, int out_size, void* d_ws, size_t ws_size,
                              hipStream_t stream) {
  const float* x    = (const float*)d_in[0];
  const float* w4   = (const float*)d_in[1];
  const float* w8   = (const float*)d_in[2];
  const int*   perm = (const int*)d_in[3];
  const float* bias = (const float*)d_in[4];
  float*       out  = (float*)d_out;

  const size_t xb_bytes = (size_t)M_DIM * K_DIM * 2;
  const size_t wb_bytes = (size_t)NT * K_DIM * 2;

  if (ws_size >= xb_bytes + wb_bytes) {
    unsigned short* xb = (unsigned short*)d_ws;
    unsigned short* wb = xb + (size_t)M_DIM * K_DIM;
    conv_x_kernel<<<2048, 256, 0, stream>>>(x, xb, (M_DIM * K_DIM) / 8);
    conv_w_kernel<<<NT, 256, 0, stream>>>(w4, w8, perm, wb);
    gemm256_kernel<<<GRID, 512, 0, stream>>>(xb, wb, bias, out);
  } else {
    int grid = (M_DIM / 128) * (NT / 128);
    gemm_fused_f32_kernel<<<grid, 256, 0, stream>>>(x, w4, w8, perm, bias, out);
  }
}

// Round 11
// 721.478 us; speedup vs baseline: 2.0211x; 2.0211x over previous
//
#include <hip/hip_runtime.h>
#include <hip/hip_bf16.h>

#define M_DIM 8192
#define K_DIM 4096
#define N4    8192
#define N8    2816
#define NT    11008   // 43 * 256
#define TM    (M_DIM / 256)   // 32
#define TN    (NT / 256)      // 43
#define NKT   (K_DIM / 64)    // 64 K-tiles
#define NFULL 1280            // 5 * 256 full-tile blocks
#define GRID  1472            // 1280 full + 192 half (96 tiles split in M)

typedef __attribute__((ext_vector_type(4))) float  f32x4;
typedef __attribute__((ext_vector_type(4))) float  float4v;
typedef __attribute__((ext_vector_type(8))) __bf16 bf16x8;
typedef __attribute__((ext_vector_type(4))) unsigned short ushort4v;
typedef __attribute__((ext_vector_type(8))) unsigned short ushort8v;

__device__ __forceinline__ unsigned short f2bf(float f) {
  union { float f; unsigned int u; } v; v.f = f;
  unsigned int u = v.u;
  unsigned int r = u + 0x7FFFu + ((u >> 16) & 1u);   // RNE
  return (unsigned short)(r >> 16);
}

// ---- x fp32 -> bf16, contiguous ----
__global__ void conv_x_kernel(const float* __restrict__ x,
                              unsigned short* __restrict__ xb, int n8) {
  int idx = blockIdx.x * blockDim.x + threadIdx.x;
  int stride = gridDim.x * blockDim.x;
  for (int i = idx; i < n8; i += stride) {
    const float4v* src = (const float4v*)(x + (size_t)i * 8);
    float4v a = src[0], b = src[1];
    ushort8v o;
    o[0] = f2bf(a[0]); o[1] = f2bf(a[1]); o[2] = f2bf(a[2]); o[3] = f2bf(a[3]);
    o[4] = f2bf(b[0]); o[5] = f2bf(b[1]); o[6] = f2bf(b[2]); o[7] = f2bf(b[3]);
    ((ushort8v*)xb)[i] = o;
  }
}

// ---- gather W_cat[inv_perm[j]] row, fp32 -> bf16 (inv_perm is int32) ----
__global__ void conv_w_kernel(const float* __restrict__ w4,
                              const float* __restrict__ w8,
                              const int* __restrict__ inv_perm,
                              unsigned short* __restrict__ wb) {
  int j = blockIdx.x;
  int c = inv_perm[j];
  const float* src = (c < N4) ? (w4 + (size_t)c * K_DIM)
                              : (w8 + (size_t)(c - N4) * K_DIM);
  unsigned short* dst = wb + (size_t)j * K_DIM;
  int t = threadIdx.x;
#pragma unroll
  for (int it = 0; it < 4; ++it) {
    int e = it * 1024 + t * 4;
    float4v a = *(const float4v*)(src + e);
    ushort4v o;
    o[0] = f2bf(a[0]); o[1] = f2bf(a[1]); o[2] = f2bf(a[2]); o[3] = f2bf(a[3]);
    *(ushort4v*)(dst + e) = o;
  }
}

// ================= 256x256 8-phase bf16 GEMM (T1+T2+T3+T4+T5) =================
// r9 schedule + register-neutral latency hiding:
//  - ph1/ph3: A reads as two 4-read groups (sched_barrier-pinned) with
//    lgkm(4) -> 8 MFMA -> lgkm(0) -> 8 MFMA split-wait.
//  - b1 reads hoisted to ph1 tail (certified by ph4(u-1) vmcnt(8)+barrier;
//    retired by ph2 lgkm0+barrier before ph3 stages B01 over those rows).
// vmcnt ledger unchanged from r8/r9 (ph2-end vmcnt(10), ph4 vmcnt(8)).
__global__ __launch_bounds__(512, 2)
void gemm256_kernel(const unsigned short* __restrict__ A,
                    const unsigned short* __restrict__ B,
                    const float* __restrict__ bias,
                    float* __restrict__ C) {
  __shared__ __align__(16) unsigned short lds[4 * 16384];  // 128 KiB

  int bid = blockIdx.x;
  int vbid, mhalf, is_half;
  if (bid < NFULL) { vbid = bid; mhalf = 0; is_half = 0; }
  else { int h = bid - NFULL; vbid = NFULL + (h >> 1); mhalf = h & 1; is_half = 1; }
  int wgid = (vbid & 7) * ((TM * TN) / 8) + (vbid >> 3);  // 1376 % 8 == 0, bijective
  int tile_m = wgid / TN;
  int tile_n = wgid % TN;

  const int tid  = threadIdx.x;
  const int wid  = tid >> 6;
  const int lane = tid & 63;
  const int wr  = wid >> 2;         // 0..1
  const int wcn = wid & 3;          // 0..3 (B quarter)
  const int l15 = lane & 15;
  // ds_read per-lane column byte offsets (swizzle folded in; row&7 == lane&7 for 16-aligned bases)
  const int rswz  = (lane & 7) << 4;
  const int coff0 = (((lane >> 4) * 16) + 0)  ^ rswz;   // kk=0
  const int coff1 = (((lane >> 4) * 16) + 64) ^ rswz;   // kk=1
  // stage per-lane source permutation: row_in_8 = lane>>3; (row&7)<<4 == (lane&0x38)<<1
  const int st_row8 = lane >> 3;
  const int st_scol = ((lane & 7) * 16) ^ ((lane & 0x38) << 1);  // bytes, < 128

  const size_t brow0 = (size_t)tile_n * 256;

  // stage one 64-row unit (8 KiB): wave wid covers rows [q*64+wid*8, +8)
  auto stage = [&](const unsigned short* __restrict__ g, size_t grow0,
                   unsigned short* ltile, int q, int ktelem) {
    int row = q * 64 + wid * 8 + st_row8;
    const unsigned short* src =
        g + (grow0 + (size_t)row) * K_DIM + ktelem + (st_scol >> 1);
    unsigned short* dst = ltile + (q * 64 + wid * 8) * 64;  // wave-uniform, linear
    __builtin_amdgcn_global_load_lds(
        (const __attribute__((address_space(1))) void*)src,
        (__attribute__((address_space(3))) void*)dst, 16, 0, 0);
  };
  auto fragld = [&](const unsigned short* ltile, int row, int coff) -> bf16x8 {
    return *(const bf16x8*)((const char*)ltile + row * 128 + coff);
  };

  if (is_half) {
    // ================== half-tile path (128x256), 3.5% of work ==============
    const size_t arowh = (size_t)tile_m * 256 + (size_t)mhalf * 128;
    f32x4 acch[4][4];
#pragma unroll
    for (int i = 0; i < 4; ++i)
#pragma unroll
      for (int j = 0; j < 4; ++j) acch[i][j] = (f32x4){0.f, 0.f, 0.f, 0.f};

    // prologue: tile0 -> buf0 (A 2 units, B 4 units)
    stage(A, arowh, lds + 0, 0, 0);      stage(A, arowh, lds + 0, 1, 0);
    stage(B, brow0, lds + 16384, 0, 0);  stage(B, brow0, lds + 16384, 1, 0);
    stage(B, brow0, lds + 16384, 2, 0);  stage(B, brow0, lds + 16384, 3, 0);
    asm volatile("s_waitcnt vmcnt(0)" ::: "memory");
    __builtin_amdgcn_s_barrier();

#pragma unroll 1
    for (int u = 0; u < NKT; ++u) {
      unsigned short* Ac = lds + (u & 1) * 32768;
      unsigned short* Bc = Ac + 16384;
      unsigned short* An = lds + (32768 - (u & 1) * 32768);
      if (u + 1 < NKT) {   // prefetch issued first; drained at iter end (latency hidden)
        int kn = (u + 1) * 64;
        stage(A, arowh, An, 0, kn);      stage(A, arowh, An, 1, kn);
        stage(B, brow0, An + 16384, 0, kn); stage(B, brow0, An + 16384, 1, kn);
        stage(B, brow0, An + 16384, 2, kn); stage(B, brow0, An + 16384, 3, kn);
      }
      bf16x8 ah[4][2], bh[4][2];
#pragma unroll
      for (int m = 0; m < 4; ++m) {
        int row = wr * 64 + m * 16 + l15;
        ah[m][0] = fragld(Ac, row, coff0);
        ah[m][1] = fragld(Ac, row, coff1);
      }
#pragma unroll
      for (int n = 0; n < 4; ++n) {
        int row = wcn * 64 + n * 16 + l15;
        bh[n][0] = fragld(Bc, row, coff0);
        bh[n][1] = fragld(Bc, row, coff1);
      }
      asm volatile("s_waitcnt lgkmcnt(0)" ::: "memory");
      __builtin_amdgcn_sched_barrier(0);
      __builtin_amdgcn_s_setprio(1);
#pragma unroll
      for (int m = 0; m < 4; ++m)
#pragma unroll
        for (int n = 0; n < 4; ++n) {
          acch[m][n] = __builtin_amdgcn_mfma_f32_16x16x32_bf16(ah[m][0], bh[n][0], acch[m][n], 0, 0, 0);
          acch[m][n] = __builtin_amdgcn_mfma_f32_16x16x32_bf16(ah[m][1], bh[n][1], acch[m][n], 0, 0, 0);
        }
      __builtin_amdgcn_s_setprio(0);
      asm volatile("s_waitcnt vmcnt(0)" ::: "memory");
      __builtin_amdgcn_s_barrier();
    }

#pragma unroll
    for (int n = 0; n < 4; ++n) {
      int col = tile_n * 256 + wcn * 64 + n * 16 + l15;
      float bv = bias[col];
#pragma unroll
      for (int m = 0; m < 4; ++m) {
        int row0 = tile_m * 256 + mhalf * 128 + wr * 64 + m * 16 + ((lane >> 4) * 4);
#pragma unroll
        for (int r = 0; r < 4; ++r) {
          C[(size_t)(row0 + r) * NT + col] = acch[m][n][r] + bv;
        }
      }
    }
    return;
  }

  // ====================== full-tile path ====================================
  const size_t arow0 = (size_t)tile_m * 256;

  f32x4 acc[8][4];
#pragma unroll
  for (int i = 0; i < 8; ++i)
#pragma unroll
    for (int j = 0; j < 4; ++j) acc[i][j] = (f32x4){0.f, 0.f, 0.f, 0.f};

  bf16x8 b0[2][2];   // loop-carried: read one phase early (ph4 of previous iter)

  // buffer layout (elements): buf0 A @0, B @16384; buf1 A @32768, B @49152

  // ---- prologue: tile0 full (8 units), tile1 A02+B01+B23 (6); tile1's A13 staged in u=0 ph1
  stage(A, arow0, lds + 0,     0, 0);  stage(A, arow0, lds + 0,     2, 0);
  stage(A, arow0, lds + 0,     1, 0);  stage(A, arow0, lds + 0,     3, 0);
  stage(B, brow0, lds + 16384, 0, 0);  stage(B, brow0, lds + 16384, 1, 0);
  stage(B, brow0, lds + 16384, 2, 0);  stage(B, brow0, lds + 16384, 3, 0);
  stage(A, arow0, lds + 32768, 0, 64); stage(A, arow0, lds + 32768, 2, 64);
  stage(B, brow0, lds + 49152, 0, 64); stage(B, brow0, lds + 49152, 1, 64);
  stage(B, brow0, lds + 49152, 2, 64); stage(B, brow0, lds + 49152, 3, 64);
  asm volatile("s_waitcnt vmcnt(6)" ::: "memory");  // tile0 (oldest 8 of 14) landed
  __builtin_amdgcn_s_barrier();

  // pre-read B0 of tile0 (4 ds ops outstanding entering ph1(0), like steady state)
#pragma unroll
  for (int n = 0; n < 2; ++n) {
    int row = wcn * 64 + n * 16 + l15;
    b0[n][0] = fragld(lds + 16384, row, coff0);
    b0[n][1] = fragld(lds + 16384, row, coff1);
  }

#define KITER(AC, BC, AN, UN1, UN2)                                           \
  {                                                                           \
    unsigned short* const Ac = (AC);                                          \
    unsigned short* const Bc = (BC);                                          \
    unsigned short* const An = (AN);                                          \
    const int un1 = (UN1);                                                    \
    const int un2 = (UN2);                                                    \
    bf16x8 a0[4][2], a1[4][2], b1[2][2];                                      \
    /* ph1: read a0 in two pinned 4-read groups; stage A13(u+1)->An;          \
       lgkm(4): b0'+a0[0..1] done -> 8 MFMA; lgkm(0) -> 8 MFMA; tail-read b1 */\
    _Pragma("unroll")                                                         \
    for (int m = 0; m < 2; ++m) {                                             \
      int row = wr * 128 + m * 16 + l15;                                      \
      a0[m][0] = fragld(Ac, row, coff0);                                      \
      a0[m][1] = fragld(Ac, row, coff1);                                      \
    }                                                                         \
    __builtin_amdgcn_sched_barrier(0);                                        \
    _Pragma("unroll")                                                         \
    for (int m = 2; m < 4; ++m) {                                             \
      int row = wr * 128 + m * 16 + l15;                                      \
      a0[m][0] = fragld(Ac, row, coff0);                                      \
      a0[m][1] = fragld(Ac, row, coff1);                                      \
    }                                                                         \
    stage(A, arow0, An, 1, un1);                                              \
    stage(A, arow0, An, 3, un1);                                              \
    __builtin_amdgcn_s_barrier();                                             \
    asm volatile("s_waitcnt lgkmcnt(4)" ::: "memory");                        \
    __builtin_amdgcn_sched_barrier(0);                                        \
    __builtin_amdgcn_s_setprio(1);                                            \
    _Pragma("unroll")                                                         \
    for (int m = 0; m < 2; ++m)                                               \
      _Pragma("unroll")                                                       \
      for (int n = 0; n < 2; ++n) {                                           \
        acc[m][n] = __builtin_amdgcn_mfma_f32_16x16x32_bf16(a0[m][0], b0[n][0], acc[m][n], 0, 0, 0); \
        acc[m][n] = __builtin_amdgcn_mfma_f32_16x16x32_bf16(a0[m][1], b0[n][1], acc[m][n], 0, 0, 0); \
      }                                                                       \
    asm volatile("s_waitcnt lgkmcnt(0)" ::: "memory");                        \
    __builtin_amdgcn_sched_barrier(0);                                        \
    _Pragma("unroll")                                                         \
    for (int m = 2; m < 4; ++m)                                               \
      _Pragma("unroll")                                                       \
      for (int n = 0; n < 2; ++n) {                                           \
        acc[m][n] = __builtin_amdgcn_mfma_f32_16x16x32_bf16(a0[m][0], b0[n][0], acc[m][n], 0, 0, 0); \
        acc[m][n] = __builtin_amdgcn_mfma_f32_16x16x32_bf16(a0[m][1], b0[n][1], acc[m][n], 0, 0, 0); \
      }                                                                       \
    __builtin_amdgcn_s_setprio(0);                                            \
    _Pragma("unroll")                                                         \
    for (int n = 0; n < 2; ++n) {  /* b1(u): certified since ph4(u-1) */      \
      int row = wcn * 64 + (2 + n) * 16 + l15;                                \
      b1[n][0] = fragld(Bc, row, coff0);                                      \
      b1[n][1] = fragld(Bc, row, coff1);                                      \
    }                                                                         \
    __builtin_amdgcn_s_barrier();                                             \
    /* ph2: stage A02(u+2)->Ac; lgkm(0) (b1 drained); mfma m0 x n1; vmcnt(10) */ \
    stage(A, arow0, Ac, 0, un2);                                              \
    stage(A, arow0, Ac, 2, un2);                                              \
    __builtin_amdgcn_s_barrier();                                             \
    asm volatile("s_waitcnt lgkmcnt(0)" ::: "memory");                        \
    __builtin_amdgcn_sched_barrier(0);                                        \
    __builtin_amdgcn_s_setprio(1);                                            \
    _Pragma("unroll")                                                         \
    for (int m = 0; m < 4; ++m)                                               \
      _Pragma("unroll")                                                       \
      for (int n = 0; n < 2; ++n) {                                           \
        acc[m][2 + n] = __builtin_amdgcn_mfma_f32_16x16x32_bf16(a0[m][0], b1[n][0], acc[m][2 + n], 0, 0, 0); \
        acc[m][2 + n] = __builtin_amdgcn_mfma_f32_16x16x32_bf16(a0[m][1], b1[n][1], acc[m][2 + n], 0, 0, 0); \
      }                                                                       \
    __builtin_amdgcn_s_setprio(0);                                            \
    asm volatile("s_waitcnt vmcnt(10)" ::: "memory"); /* A13(u) landed */     \
    __builtin_amdgcn_s_barrier();                                             \
    /* ph3: read a1 in two pinned groups; stage B01(u+2)->Bc;                 \
       lgkm(4) -> 8 MFMA -> lgkm(0) -> 8 MFMA */                              \
    _Pragma("unroll")                                                         \
    for (int m = 0; m < 2; ++m) {                                             \
      int row = wr * 128 + 64 + m * 16 + l15;                                 \
      a1[m][0] = fragld(Ac, row, coff0);                                      \
      a1[m][1] = fragld(Ac, row, coff1);                                      \
    }                                                                         \
    __builtin_amdgcn_sched_barrier(0);                                        \
    _Pragma("unroll")                                                         \
    for (int m = 2; m < 4; ++m) {                                             \
      int row = wr * 128 + 64 + m * 16 + l15;                                 \
      a1[m][0] = fragld(Ac, row, coff0);                                      \
      a1[m][1] = fragld(Ac, row, coff1);                                      \
    }                                                                         \
    stage(B, brow0, Bc, 0, un2);                                              \
    stage(B, brow0, Bc, 1, un2);                                              \
    __builtin_amdgcn_s_barrier();                                             \
    asm volatile("s_waitcnt lgkmcnt(4)" ::: "memory");                        \
    __builtin_amdgcn_sched_barrier(0);                                        \
    __builtin_amdgcn_s_setprio(1);                                            \
    _Pragma("unroll")                                                         \
    for (int m = 0; m < 2; ++m)                                               \
      _Pragma("unroll")                                                       \
      for (int n = 0; n < 2; ++n) {                                           \
        acc[4 + m][n] = __builtin_amdgcn_mfma_f32_16x16x32_bf16(a1[m][0], b0[n][0], acc[4 + m][n], 0, 0, 0); \
        acc[4 + m][n] = __builtin_amdgcn_mfma_f32_16x16x32_bf16(a1[m][1], b0[n][1], acc[4 + m][n], 0, 0, 0); \
      }                                                                       \
    asm volatile("s_waitcnt lgkmcnt(0)" ::: "memory");                        \
    __builtin_amdgcn_sched_barrier(0);                                        \
    _Pragma("unroll")                                                         \
    for (int m = 2; m < 4; ++m)                                               \
      _Pragma("unroll")                                                       \
      for (int n = 0; n < 2; ++n) {                                           \
        acc[4 + m][n] = __builtin_amdgcn_mfma_f32_16x16x32_bf16(a1[m][0], b0[n][0], acc[4 + m][n], 0, 0, 0); \
        acc[4 + m][n] = __builtin_amdgcn_mfma_f32_16x16x32_bf16(a1[m][1], b0[n][1], acc[4 + m][n], 0, 0, 0); \
      }                                                                       \
    __builtin_amdgcn_s_setprio(0);                                            \
    __builtin_amdgcn_s_barrier();                                             \
    /* ph4: stage B23(u+2)->Bc; vmcnt(8): A02/B01/B23(u+1) landed;            \
       read b0(u+1) from An's B half (overlaps MFMA); mfma m1 x n1 */         \
    stage(B, brow0, Bc, 2, un2);                                              \
    stage(B, brow0, Bc, 3, un2);                                              \
    asm volatile("s_waitcnt vmcnt(8)" ::: "memory");                          \
    __builtin_amdgcn_s_barrier();                                             \
    _Pragma("unroll")                                                         \
    for (int n = 0; n < 2; ++n) {                                             \
      int row = wcn * 64 + n * 16 + l15;                                      \
      b0[n][0] = fragld(An + 16384, row, coff0);                              \
      b0[n][1] = fragld(An + 16384, row, coff1);                              \
    }                                                                         \
    __builtin_amdgcn_s_setprio(1);                                            \
    _Pragma("unroll")                                                         \
    for (int m = 0; m < 4; ++m)                                               \
      _Pragma("unroll")                                                       \
      for (int n = 0; n < 2; ++n) {                                           \
        acc[4 + m][2 + n] = __builtin_amdgcn_mfma_f32_16x16x32_bf16(a1[m][0], b1[n][0], acc[4 + m][2 + n], 0, 0, 0); \
        acc[4 + m][2 + n] = __builtin_amdgcn_mfma_f32_16x16x32_bf16(a1[m][1], b1[n][1], acc[4 + m][2 + n], 0, 0, 0); \
      }                                                                       \
    __builtin_amdgcn_s_setprio(0);                                            \
    __builtin_amdgcn_s_barrier();                                             \
  }

#pragma unroll 1
  for (int u = 0; u < NKT; u += 2) {
    const int k1 = ((u + 1 < NKT) ? (u + 1) : (NKT - 1)) * 64;
    const int k2 = ((u + 2 < NKT) ? (u + 2) : (NKT - 1)) * 64;
    const int k3 = ((u + 3 < NKT) ? (u + 3) : (NKT - 1)) * 64;
    // even iter: buf0 current, buf1 next
    KITER(lds + 0,     lds + 16384, lds + 32768, k1, k2);
    // odd iter: buf1 current, buf0 next
    KITER(lds + 32768, lds + 49152, lds + 0,     k2, k3);
  }
#undef KITER

  // ---- epilogue: C/D layout col=lane&15, row=(lane>>4)*4+r
#pragma unroll
  for (int n = 0; n < 4; ++n) {
    int col = tile_n * 256 + wcn * 64 + n * 16 + l15;
    float bv = bias[col];
#pragma unroll
    for (int m = 0; m < 8; ++m) {
      int row0 = tile_m * 256 + wr * 128 + m * 16 + ((lane >> 4) * 4);
#pragma unroll
      for (int r = 0; r < 4; ++r) {
        C[(size_t)(row0 + r) * NT + col] = acc[m][n][r] + bv;
      }
    }
  }
}

// ============ fallback path: no workspace, fp32 sources, reg convert ========
__global__ void gemm_fused_f32_kernel(const float* __restrict__ x,
                                      const float* __restrict__ w4,
                                      const float* __restrict__ w8,
                                      const int* __restrict__ inv_perm,
                                      const float* __restrict__ bias,
                                      float* __restrict__ C) {
  __shared__ __align__(16) unsigned short Alds[128 * 64];
  __shared__ __align__(16) unsigned short Blds[128 * 64];

  int bid = blockIdx.x;
  int wgid = (bid & 7) * ((M_DIM / 128) * (NT / 128) / 8) + (bid >> 3);
  int tile_n = wgid % (NT / 128);
  int tile_m = wgid / (NT / 128);

  const int tid  = threadIdx.x;
  const int wid  = tid >> 6;
  const int lane = tid & 63;
  const int wr = wid >> 1, wc = wid & 1;

  f32x4 acc[4][4];
#pragma unroll
  for (int i = 0; i < 4; ++i)
#pragma unroll
    for (int j = 0; j < 4; ++j) acc[i][j] = (f32x4){0.f, 0.f, 0.f, 0.f};

  const int lrow = lane >> 3;
  const int lcol = (lane & 7) * 8;

  const float* asrc[4];
  const float* bsrc[4];
  int ldsoff[4];
#pragma unroll
  for (int s = 0; s < 4; ++s) {
    int rb = s * 32 + wid * 8 + lrow;
    asrc[s] = x + (size_t)(tile_m * 128 + rb) * K_DIM + lcol;
    int c = inv_perm[tile_n * 128 + rb];
    bsrc[s] = ((c < N4) ? (w4 + (size_t)c * K_DIM)
                        : (w8 + (size_t)(c - N4) * K_DIM)) + lcol;
    ldsoff[s] = rb * 64 + lcol;
  }

  for (int kt = 0; kt < K_DIM; kt += 64) {
#pragma unroll
    for (int s = 0; s < 4; ++s) {
      float4v a0 = *(const float4v*)(asrc[s] + kt);
      float4v a1 = *(const float4v*)(asrc[s] + kt + 4);
      float4v b0 = *(const float4v*)(bsrc[s] + kt);
      float4v b1 = *(const float4v*)(bsrc[s] + kt + 4);
      ushort8v oa, ob;
      oa[0]=f2bf(a0[0]); oa[1]=f2bf(a0[1]); oa[2]=f2bf(a0[2]); oa[3]=f2bf(a0[3]);
      oa[4]=f2bf(a1[0]); oa[5]=f2bf(a1[1]); oa[6]=f2bf(a1[2]); oa[7]=f2bf(a1[3]);
      ob[0]=f2bf(b0[0]); ob[1]=f2bf(b0[1]); ob[2]=f2bf(b0[2]); ob[3]=f2bf(b0[3]);
      ob[4]=f2bf(b1[0]); ob[5]=f2bf(b1[1]); ob[6]=f2bf(b1[2]); ob[7]=f2bf(b1[3]);
      *(ushort8v*)&Alds[ldsoff[s]] = oa;
      *(ushort8v*)&Blds[ldsoff[s]] = ob;
    }
    __syncthreads();

#pragma unroll
    for (int kk = 0; kk < 2; ++kk) {
      bf16x8 af[4], bfr[4];
#pragma unroll
      for (int i = 0; i < 4; ++i) {
        int row = wr * 64 + i * 16 + (lane & 15);
        af[i] = *(const bf16x8*)&Alds[row * 64 + kk * 32 + (lane >> 4) * 8];
      }
#pragma unroll
      for (int j = 0; j < 4; ++j) {
        int row = wc * 64 + j * 16 + (lane & 15);
        bfr[j] = *(const bf16x8*)&Blds[row * 64 + kk * 32 + (lane >> 4) * 8];
      }
#pragma unroll
      for (int i = 0; i < 4; ++i)
#pragma unroll
        for (int j = 0; j < 4; ++j)
          acc[i][j] = __builtin_amdgcn_mfma_f32_16x16x32_bf16(af[i], bfr[j], acc[i][j], 0, 0, 0);
    }
    __syncthreads();
  }

#pragma unroll
  for (int j = 0; j < 4; ++j) {
    int col = tile_n * 128 + wc * 64 + j * 16 + (lane & 15);
    float bv = bias[col];
#pragma unroll
    for (int i = 0; i < 4; ++i) {
      int row0 = tile_m * 128 + wr * 64 + i * 16 + ((lane >> 4) * 4);
#pragma unroll
      for (int r = 0; r < 4; ++r) {
        C[(size_t)(row0 + r) * NT + col] = acc[i][j][r] + bv;
      }
    }
  }
}

extern "C" void kernel_launch(void* const* d_in, const int* in_sizes, int n_in,
                              void* d_out, int out_size, void* d_ws, size_t ws_size,
                              hipStream_t stream) {
  const float* x    = (const float*)d_in[0];
  const float* w4   = (const float*)d_in[1];
  const float* w8   = (const float*)d_in[2];
  const int*   perm = (const int*)d_in[3];
  const float* bias = (const float*)d_in[4];
  float*       out  = (float*)d_out;

  const size_t xb_bytes = (size_t)M_DIM * K_DIM * 2;
  const size_t wb_bytes = (size_t)NT * K_DIM * 2;

  if (ws_size >= xb_bytes + wb_bytes) {
    unsigned short* xb = (unsigned short*)d_ws;
    unsigned short* wb = xb + (size_t)M_DIM * K_DIM;
    conv_x_kernel<<<2048, 256, 0, stream>>>(x, xb, (M_DIM * K_DIM) / 8);
    conv_w_kernel<<<NT, 256, 0, stream>>>(w4, w8, perm, wb);
    gemm256_kernel<<<GRID, 512, 0, stream>>>(xb, wb, bias, out);
  } else {
    int grid = (M_DIM / 128) * (NT / 128);
    gemm_fused_f32_kernel<<<grid, 256, 0, stream>>>(x, w4, w8, perm, bias, out);
  }
}

// Round 12
// 718.123 us; speedup vs baseline: 2.0306x; 1.0047x over previous
//
#include <hip/hip_runtime.h>
#include <hip/hip_bf16.h>

#define M_DIM 8192
#define K_DIM 4096
#define N4    8192
#define N8    2816
#define NT    11008   // 43 * 256
#define TM    (M_DIM / 256)   // 32
#define TN    (NT / 256)      // 43
#define NKT   (K_DIM / 64)    // 64 K-tiles
#define NFULL 1280            // 5 * 256 full-tile blocks
#define GRID  1472            // 1280 full + 192 half (96 tiles split in M)

typedef __attribute__((ext_vector_type(4))) float  f32x4;
typedef __attribute__((ext_vector_type(4))) float  float4v;
typedef __attribute__((ext_vector_type(8))) __bf16 bf16x8;
typedef __attribute__((ext_vector_type(4))) unsigned short ushort4v;
typedef __attribute__((ext_vector_type(8))) unsigned short ushort8v;

__device__ __forceinline__ unsigned short f2bf(float f) {
  union { float f; unsigned int u; } v; v.f = f;
  unsigned int u = v.u;
  unsigned int r = u + 0x7FFFu + ((u >> 16) & 1u);   // RNE
  return (unsigned short)(r >> 16);
}

// ---- x fp32 -> bf16, contiguous ----
__global__ void conv_x_kernel(const float* __restrict__ x,
                              unsigned short* __restrict__ xb, int n8) {
  int idx = blockIdx.x * blockDim.x + threadIdx.x;
  int stride = gridDim.x * blockDim.x;
  for (int i = idx; i < n8; i += stride) {
    const float4v* src = (const float4v*)(x + (size_t)i * 8);
    float4v a = src[0], b = src[1];
    ushort8v o;
    o[0] = f2bf(a[0]); o[1] = f2bf(a[1]); o[2] = f2bf(a[2]); o[3] = f2bf(a[3]);
    o[4] = f2bf(b[0]); o[5] = f2bf(b[1]); o[6] = f2bf(b[2]); o[7] = f2bf(b[3]);
    ((ushort8v*)xb)[i] = o;
  }
}

// ---- gather W_cat[inv_perm[j]] row, fp32 -> bf16 (inv_perm is int32) ----
__global__ void conv_w_kernel(const float* __restrict__ w4,
                              const float* __restrict__ w8,
                              const int* __restrict__ inv_perm,
                              unsigned short* __restrict__ wb) {
  int j = blockIdx.x;
  int c = inv_perm[j];
  const float* src = (c < N4) ? (w4 + (size_t)c * K_DIM)
                              : (w8 + (size_t)(c - N4) * K_DIM);
  unsigned short* dst = wb + (size_t)j * K_DIM;
  int t = threadIdx.x;
#pragma unroll
  for (int it = 0; it < 4; ++it) {
    int e = it * 1024 + t * 4;
    float4v a = *(const float4v*)(src + e);
    ushort4v o;
    o[0] = f2bf(a[0]); o[1] = f2bf(a[1]); o[2] = f2bf(a[2]); o[3] = f2bf(a[3]);
    *(ushort4v*)(dst + e) = o;
  }
}

// ================= 256x256 8-phase bf16 GEMM (T1+T2+T3+T4+T5) =================
// r11 schedule, byte-identical sync/ledger; stage addressing strength-reduced:
// per-lane 64-bit src base pointers precomputed once, each stage = base +
// const_q_offset + kt (one add). LDS dst = ltile + q*4096 + wid*512 (const).
__global__ __launch_bounds__(512, 2)
void gemm256_kernel(const unsigned short* __restrict__ A,
                    const unsigned short* __restrict__ B,
                    const float* __restrict__ bias,
                    float* __restrict__ C) {
  __shared__ __align__(16) unsigned short lds[4 * 16384];  // 128 KiB

  int bid = blockIdx.x;
  int vbid, mhalf, is_half;
  if (bid < NFULL) { vbid = bid; mhalf = 0; is_half = 0; }
  else { int h = bid - NFULL; vbid = NFULL + (h >> 1); mhalf = h & 1; is_half = 1; }
  int wgid = (vbid & 7) * ((TM * TN) / 8) + (vbid >> 3);  // 1376 % 8 == 0, bijective
  int tile_m = wgid / TN;
  int tile_n = wgid % TN;

  const int tid  = threadIdx.x;
  const int wid  = tid >> 6;
  const int lane = tid & 63;
  const int wr  = wid >> 2;         // 0..1
  const int wcn = wid & 3;          // 0..3 (B quarter)
  const int l15 = lane & 15;
  // ds_read per-lane column byte offsets (swizzle folded in; row&7 == lane&7 for 16-aligned bases)
  const int rswz  = (lane & 7) << 4;
  const int coff0 = (((lane >> 4) * 16) + 0)  ^ rswz;   // kk=0
  const int coff1 = (((lane >> 4) * 16) + 64) ^ rswz;   // kk=1
  // stage per-lane source permutation: row_in_8 = lane>>3; (row&7)<<4 == (lane&0x38)<<1
  const int st_row8 = lane >> 3;
  const int st_scol = ((lane & 7) * 16) ^ ((lane & 0x38) << 1);  // bytes, < 128
  const int dstoff  = wid * 512;    // (wid*8 rows) * 64 elem

  const size_t brow0 = (size_t)tile_n * 256;

  // per-lane staging source base (row/swizzle folded); unit q adds q*64*K_DIM
  const unsigned short* bS =
      B + (brow0 + (size_t)(wid * 8 + st_row8)) * K_DIM + (st_scol >> 1);

  // stage one 64-row unit (8 KiB): wave wid covers rows [q*64+wid*8, +8)
  auto stage = [&](const unsigned short* __restrict__ srcb,
                   unsigned short* ltile, int q, int ktelem) {
    __builtin_amdgcn_global_load_lds(
        (const __attribute__((address_space(1))) void*)(srcb + q * (64 * K_DIM) + ktelem),
        (__attribute__((address_space(3))) void*)(ltile + q * 4096 + dstoff), 16, 0, 0);
  };
  auto fragld = [&](const unsigned short* ltile, int row, int coff) -> bf16x8 {
    return *(const bf16x8*)((const char*)ltile + row * 128 + coff);
  };

  if (is_half) {
    // ================== half-tile path (128x256), 3.5% of work ==============
    const unsigned short* aSh =
        A + ((size_t)tile_m * 256 + (size_t)mhalf * 128 + (size_t)(wid * 8 + st_row8)) * K_DIM
          + (st_scol >> 1);
    f32x4 acch[4][4];
#pragma unroll
    for (int i = 0; i < 4; ++i)
#pragma unroll
      for (int j = 0; j < 4; ++j) acch[i][j] = (f32x4){0.f, 0.f, 0.f, 0.f};

    // prologue: tile0 -> buf0 (A 2 units, B 4 units)
    stage(aSh, lds + 0, 0, 0);      stage(aSh, lds + 0, 1, 0);
    stage(bS, lds + 16384, 0, 0);   stage(bS, lds + 16384, 1, 0);
    stage(bS, lds + 16384, 2, 0);   stage(bS, lds + 16384, 3, 0);
    asm volatile("s_waitcnt vmcnt(0)" ::: "memory");
    __builtin_amdgcn_s_barrier();

#pragma unroll 1
    for (int u = 0; u < NKT; ++u) {
      unsigned short* Ac = lds + (u & 1) * 32768;
      unsigned short* Bc = Ac + 16384;
      unsigned short* An = lds + (32768 - (u & 1) * 32768);
      if (u + 1 < NKT) {   // prefetch issued first; drained at iter end (latency hidden)
        int kn = (u + 1) * 64;
        stage(aSh, An, 0, kn);      stage(aSh, An, 1, kn);
        stage(bS, An + 16384, 0, kn); stage(bS, An + 16384, 1, kn);
        stage(bS, An + 16384, 2, kn); stage(bS, An + 16384, 3, kn);
      }
      bf16x8 ah[4][2], bh[4][2];
#pragma unroll
      for (int m = 0; m < 4; ++m) {
        int row = wr * 64 + m * 16 + l15;
        ah[m][0] = fragld(Ac, row, coff0);
        ah[m][1] = fragld(Ac, row, coff1);
      }
#pragma unroll
      for (int n = 0; n < 4; ++n) {
        int row = wcn * 64 + n * 16 + l15;
        bh[n][0] = fragld(Bc, row, coff0);
        bh[n][1] = fragld(Bc, row, coff1);
      }
      asm volatile("s_waitcnt lgkmcnt(0)" ::: "memory");
      __builtin_amdgcn_sched_barrier(0);
      __builtin_amdgcn_s_setprio(1);
#pragma unroll
      for (int m = 0; m < 4; ++m)
#pragma unroll
        for (int n = 0; n < 4; ++n) {
          acch[m][n] = __builtin_amdgcn_mfma_f32_16x16x32_bf16(ah[m][0], bh[n][0], acch[m][n], 0, 0, 0);
          acch[m][n] = __builtin_amdgcn_mfma_f32_16x16x32_bf16(ah[m][1], bh[n][1], acch[m][n], 0, 0, 0);
        }
      __builtin_amdgcn_s_setprio(0);
      asm volatile("s_waitcnt vmcnt(0)" ::: "memory");
      __builtin_amdgcn_s_barrier();
    }

#pragma unroll
    for (int n = 0; n < 4; ++n) {
      int col = tile_n * 256 + wcn * 64 + n * 16 + l15;
      float bv = bias[col];
#pragma unroll
      for (int m = 0; m < 4; ++m) {
        int row0 = tile_m * 256 + mhalf * 128 + wr * 64 + m * 16 + ((lane >> 4) * 4);
#pragma unroll
        for (int r = 0; r < 4; ++r) {
          C[(size_t)(row0 + r) * NT + col] = acch[m][n][r] + bv;
        }
      }
    }
    return;
  }

  // ====================== full-tile path ====================================
  const unsigned short* aS =
      A + ((size_t)tile_m * 256 + (size_t)(wid * 8 + st_row8)) * K_DIM + (st_scol >> 1);

  f32x4 acc[8][4];
#pragma unroll
  for (int i = 0; i < 8; ++i)
#pragma unroll
    for (int j = 0; j < 4; ++j) acc[i][j] = (f32x4){0.f, 0.f, 0.f, 0.f};

  bf16x8 b0[2][2];   // loop-carried: read one phase early (ph4 of previous iter)

  // buffer layout (elements): buf0 A @0, B @16384; buf1 A @32768, B @49152

  // ---- prologue: tile0 full (8 units), tile1 A02+B01+B23 (6); tile1's A13 staged in u=0 ph1
  stage(aS, lds + 0,     0, 0);  stage(aS, lds + 0,     2, 0);
  stage(aS, lds + 0,     1, 0);  stage(aS, lds + 0,     3, 0);
  stage(bS, lds + 16384, 0, 0);  stage(bS, lds + 16384, 1, 0);
  stage(bS, lds + 16384, 2, 0);  stage(bS, lds + 16384, 3, 0);
  stage(aS, lds + 32768, 0, 64); stage(aS, lds + 32768, 2, 64);
  stage(bS, lds + 49152, 0, 64); stage(bS, lds + 49152, 1, 64);
  stage(bS, lds + 49152, 2, 64); stage(bS, lds + 49152, 3, 64);
  asm volatile("s_waitcnt vmcnt(6)" ::: "memory");  // tile0 (oldest 8 of 14) landed
  __builtin_amdgcn_s_barrier();

  // pre-read B0 of tile0 (4 ds ops outstanding entering ph1(0), like steady state)
#pragma unroll
  for (int n = 0; n < 2; ++n) {
    int row = wcn * 64 + n * 16 + l15;
    b0[n][0] = fragld(lds + 16384, row, coff0);
    b0[n][1] = fragld(lds + 16384, row, coff1);
  }

#define KITER(AC, BC, AN, UN1, UN2)                                           \
  {                                                                           \
    unsigned short* const Ac = (AC);                                          \
    unsigned short* const Bc = (BC);                                          \
    unsigned short* const An = (AN);                                          \
    const int un1 = (UN1);                                                    \
    const int un2 = (UN2);                                                    \
    bf16x8 a0[4][2], a1[4][2], b1[2][2];                                      \
    /* ph1: read a0 in two pinned 4-read groups; stage A13(u+1)->An;          \
       lgkm(4): b0'+a0[0..1] done -> 8 MFMA; lgkm(0) -> 8 MFMA; tail-read b1 */\
    _Pragma("unroll")                                                         \
    for (int m = 0; m < 2; ++m) {                                             \
      int row = wr * 128 + m * 16 + l15;                                      \
      a0[m][0] = fragld(Ac, row, coff0);                                      \
      a0[m][1] = fragld(Ac, row, coff1);                                      \
    }                                                                         \
    __builtin_amdgcn_sched_barrier(0);                                        \
    _Pragma("unroll")                                                         \
    for (int m = 2; m < 4; ++m) {                                             \
      int row = wr * 128 + m * 16 + l15;                                      \
      a0[m][0] = fragld(Ac, row, coff0);                                      \
      a0[m][1] = fragld(Ac, row, coff1);                                      \
    }                                                                         \
    stage(aS, An, 1, un1);                                                    \
    stage(aS, An, 3, un1);                                                    \
    __builtin_amdgcn_s_barrier();                                             \
    asm volatile("s_waitcnt lgkmcnt(4)" ::: "memory");                        \
    __builtin_amdgcn_sched_barrier(0);                                        \
    __builtin_amdgcn_s_setprio(1);                                            \
    _Pragma("unroll")                                                         \
    for (int m = 0; m < 2; ++m)                                               \
      _Pragma("unroll")                                                       \
      for (int n = 0; n < 2; ++n) {                                           \
        acc[m][n] = __builtin_amdgcn_mfma_f32_16x16x32_bf16(a0[m][0], b0[n][0], acc[m][n], 0, 0, 0); \
        acc[m][n] = __builtin_amdgcn_mfma_f32_16x16x32_bf16(a0[m][1], b0[n][1], acc[m][n], 0, 0, 0); \
      }                                                                       \
    asm volatile("s_waitcnt lgkmcnt(0)" ::: "memory");                        \
    __builtin_amdgcn_sched_barrier(0);                                        \
    _Pragma("unroll")                                                         \
    for (int m = 2; m < 4; ++m)                                               \
      _Pragma("unroll")                                                       \
      for (int n = 0; n < 2; ++n) {                                           \
        acc[m][n] = __builtin_amdgcn_mfma_f32_16x16x32_bf16(a0[m][0], b0[n][0], acc[m][n], 0, 0, 0); \
        acc[m][n] = __builtin_amdgcn_mfma_f32_16x16x32_bf16(a0[m][1], b0[n][1], acc[m][n], 0, 0, 0); \
      }                                                                       \
    __builtin_amdgcn_s_setprio(0);                                            \
    _Pragma("unroll")                                                         \
    for (int n = 0; n < 2; ++n) {  /* b1(u): certified since ph4(u-1) */      \
      int row = wcn * 64 + (2 + n) * 16 + l15;                                \
      b1[n][0] = fragld(Bc, row, coff0);                                      \
      b1[n][1] = fragld(Bc, row, coff1);                                      \
    }                                                                         \
    __builtin_amdgcn_s_barrier();                                             \
    /* ph2: stage A02(u+2)->Ac; lgkm(0) (b1 drained); mfma m0 x n1; vmcnt(10) */ \
    stage(aS, Ac, 0, un2);                                                    \
    stage(aS, Ac, 2, un2);                                                    \
    __builtin_amdgcn_s_barrier();                                             \
    asm volatile("s_waitcnt lgkmcnt(0)" ::: "memory");                        \
    __builtin_amdgcn_sched_barrier(0);                                        \
    __builtin_amdgcn_s_setprio(1);                                            \
    _Pragma("unroll")                                                         \
    for (int m = 0; m < 4; ++m)                                               \
      _Pragma("unroll")                                                       \
      for (int n = 0; n < 2; ++n) {                                           \
        acc[m][2 + n] = __builtin_amdgcn_mfma_f32_16x16x32_bf16(a0[m][0], b1[n][0], acc[m][2 + n], 0, 0, 0); \
        acc[m][2 + n] = __builtin_amdgcn_mfma_f32_16x16x32_bf16(a0[m][1], b1[n][1], acc[m][2 + n], 0, 0, 0); \
      }                                                                       \
    __builtin_amdgcn_s_setprio(0);                                            \
    asm volatile("s_waitcnt vmcnt(10)" ::: "memory"); /* A13(u) landed */     \
    __builtin_amdgcn_s_barrier();                                             \
    /* ph3: read a1 in two pinned groups; stage B01(u+2)->Bc;                 \
       lgkm(4) -> 8 MFMA -> lgkm(0) -> 8 MFMA */                              \
    _Pragma("unroll")                                                         \
    for (int m = 0; m < 2; ++m) {                                             \
      int row = wr * 128 + 64 + m * 16 + l15;                                 \
      a1[m][0] = fragld(Ac, row, coff0);                                      \
      a1[m][1] = fragld(Ac, row, coff1);                                      \
    }                                                                         \
    __builtin_amdgcn_sched_barrier(0);                                        \
    _Pragma("unroll")                                                         \
    for (int m = 2; m < 4; ++m) {                                             \
      int row = wr * 128 + 64 + m * 16 + l15;                                 \
      a1[m][0] = fragld(Ac, row, coff0);                                      \
      a1[m][1] = fragld(Ac, row, coff1);                                      \
    }                                                                         \
    stage(bS, Bc, 0, un2);                                                    \
    stage(bS, Bc, 1, un2);                                                    \
    __builtin_amdgcn_s_barrier();                                             \
    asm volatile("s_waitcnt lgkmcnt(4)" ::: "memory");                        \
    __builtin_amdgcn_sched_barrier(0);                                        \
    __builtin_amdgcn_s_setprio(1);                                            \
    _Pragma("unroll")                                                         \
    for (int m = 0; m < 2; ++m)                                               \
      _Pragma("unroll")                                                       \
      for (int n = 0; n < 2; ++n) {                                           \
        acc[4 + m][n] = __builtin_amdgcn_mfma_f32_16x16x32_bf16(a1[m][0], b0[n][0], acc[4 + m][n], 0, 0, 0); \
        acc[4 + m][n] = __builtin_amdgcn_mfma_f32_16x16x32_bf16(a1[m][1], b0[n][1], acc[4 + m][n], 0, 0, 0); \
      }                                                                       \
    asm volatile("s_waitcnt lgkmcnt(0)" ::: "memory");                        \
    __builtin_amdgcn_sched_barrier(0);                                        \
    _Pragma("unroll")                                                         \
    for (int m = 2; m < 4; ++m)                                               \
      _Pragma("unroll")                                                       \
      for (int n = 0; n < 2; ++n) {                                           \
        acc[4 + m][n] = __builtin_amdgcn_mfma_f32_16x16x32_bf16(a1[m][0], b0[n][0], acc[4 + m][n], 0, 0, 0); \
        acc[4 + m][n] = __builtin_amdgcn_mfma_f32_16x16x32_bf16(a1[m][1], b0[n][1], acc[4 + m][n], 0, 0, 0); \
      }                                                                       \
    __builtin_amdgcn_s_setprio(0);                                            \
    __builtin_amdgcn_s_barrier();                                             \
    /* ph4: stage B23(u+2)->Bc; vmcnt(8): A02/B01/B23(u+1) landed;            \
       read b0(u+1) from An's B half (overlaps MFMA); mfma m1 x n1 */         \
    stage(bS, Bc, 2, un2);                                                    \
    stage(bS, Bc, 3, un2);                                                    \
    asm volatile("s_waitcnt vmcnt(8)" ::: "memory");                          \
    __builtin_amdgcn_s_barrier();                                             \
    _Pragma("unroll")                                                         \
    for (int n = 0; n < 2; ++n) {                                             \
      int row = wcn * 64 + n * 16 + l15;                                      \
      b0[n][0] = fragld(An + 16384, row, coff0);                              \
      b0[n][1] = fragld(An + 16384, row, coff1);                              \
    }                                                                         \
    __builtin_amdgcn_s_setprio(1);                                            \
    _Pragma("unroll")                                                         \
    for (int m = 0; m < 4; ++m)                                               \
      _Pragma("unroll")                                                       \
      for (int n = 0; n < 2; ++n) {                                           \
        acc[4 + m][2 + n] = __builtin_amdgcn_mfma_f32_16x16x32_bf16(a1[m][0], b1[n][0], acc[4 + m][2 + n], 0, 0, 0); \
        acc[4 + m][2 + n] = __builtin_amdgcn_mfma_f32_16x16x32_bf16(a1[m][1], b1[n][1], acc[4 + m][2 + n], 0, 0, 0); \
      }                                                                       \
    __builtin_amdgcn_s_setprio(0);                                            \
    __builtin_amdgcn_s_barrier();                                             \
  }

#pragma unroll 1
  for (int u = 0; u < NKT; u += 2) {
    const int k1 = ((u + 1 < NKT) ? (u + 1) : (NKT - 1)) * 64;
    const int k2 = ((u + 2 < NKT) ? (u + 2) : (NKT - 1)) * 64;
    const int k3 = ((u + 3 < NKT) ? (u + 3) : (NKT - 1)) * 64;
    // even iter: buf0 current, buf1 next
    KITER(lds + 0,     lds + 16384, lds + 32768, k1, k2);
    // odd iter: buf1 current, buf0 next
    KITER(lds + 32768, lds + 49152, lds + 0,     k2, k3);
  }
#undef KITER

  // ---- epilogue: C/D layout col=lane&15, row=(lane>>4)*4+r
#pragma unroll
  for (int n = 0; n < 4; ++n) {
    int col = tile_n * 256 + wcn * 64 + n * 16 + l15;
    float bv = bias[col];
#pragma unroll
    for (int m = 0; m < 8; ++m) {
      int row0 = tile_m * 256 + wr * 128 + m * 16 + ((lane >> 4) * 4);
#pragma unroll
      for (int r = 0; r < 4; ++r) {
        C[(size_t)(row0 + r) * NT + col] = acc[m][n][r] + bv;
      }
    }
  }
}

// ============ fallback path: no workspace, fp32 sources, reg convert ========
__global__ void gemm_fused_f32_kernel(const float* __restrict__ x,
                                      const float* __restrict__ w4,
                                      const float* __restrict__ w8,
                                      const int* __restrict__ inv_perm,
                                      const float* __restrict__ bias,
                                      float* __restrict__ C) {
  __shared__ __align__(16) unsigned short Alds[128 * 64];
  __shared__ __align__(16) unsigned short Blds[128 * 64];

  int bid = blockIdx.x;
  int wgid = (bid & 7) * ((M_DIM / 128) * (NT / 128) / 8) + (bid >> 3);
  int tile_n = wgid % (NT / 128);
  int tile_m = wgid / (NT / 128);

  const int tid  = threadIdx.x;
  const int wid  = tid >> 6;
  const int lane = tid & 63;
  const int wr = wid >> 1, wc = wid & 1;

  f32x4 acc[4][4];
#pragma unroll
  for (int i = 0; i < 4; ++i)
#pragma unroll
    for (int j = 0; j < 4; ++j) acc[i][j] = (f32x4){0.f, 0.f, 0.f, 0.f};

  const int lrow = lane >> 3;
  const int lcol = (lane & 7) * 8;

  const float* asrc[4];
  const float* bsrc[4];
  int ldsoff[4];
#pragma unroll
  for (int s = 0; s < 4; ++s) {
    int rb = s * 32 + wid * 8 + lrow;
    asrc[s] = x + (size_t)(tile_m * 128 + rb) * K_DIM + lcol;
    int c = inv_perm[tile_n * 128 + rb];
    bsrc[s] = ((c < N4) ? (w4 + (size_t)c * K_DIM)
                        : (w8 + (size_t)(c - N4) * K_DIM)) + lcol;
    ldsoff[s] = rb * 64 + lcol;
  }

  for (int kt = 0; kt < K_DIM; kt += 64) {
#pragma unroll
    for (int s = 0; s < 4; ++s) {
      float4v a0 = *(const float4v*)(asrc[s] + kt);
      float4v a1 = *(const float4v*)(asrc[s] + kt + 4);
      float4v b0 = *(const float4v*)(bsrc[s] + kt);
      float4v b1 = *(const float4v*)(bsrc[s] + kt + 4);
      ushort8v oa, ob;
      oa[0]=f2bf(a0[0]); oa[1]=f2bf(a0[1]); oa[2]=f2bf(a0[2]); oa[3]=f2bf(a0[3]);
      oa[4]=f2bf(a1[0]); oa[5]=f2bf(a1[1]); oa[6]=f2bf(a1[2]); oa[7]=f2bf(a1[3]);
      ob[0]=f2bf(b0[0]); ob[1]=f2bf(b0[1]); ob[2]=f2bf(b0[2]); ob[3]=f2bf(b0[3]);
      ob[4]=f2bf(b1[0]); ob[5]=f2bf(b1[1]); ob[6]=f2bf(b1[2]); ob[7]=f2bf(b1[3]);
      *(ushort8v*)&Alds[ldsoff[s]] = oa;
      *(ushort8v*)&Blds[ldsoff[s]] = ob;
    }
    __syncthreads();

#pragma unroll
    for (int kk = 0; kk < 2; ++kk) {
      bf16x8 af[4], bfr[4];
#pragma unroll
      for (int i = 0; i < 4; ++i) {
        int row = wr * 64 + i * 16 + (lane & 15);
        af[i] = *(const bf16x8*)&Alds[row * 64 + kk * 32 + (lane >> 4) * 8];
      }
#pragma unroll
      for (int j = 0; j < 4; ++j) {
        int row = wc * 64 + j * 16 + (lane & 15);
        bfr[j] = *(const bf16x8*)&Blds[row * 64 + kk * 32 + (lane >> 4) * 8];
      }
#pragma unroll
      for (int i = 0; i < 4; ++i)
#pragma unroll
        for (int j = 0; j < 4; ++j)
          acc[i][j] = __builtin_amdgcn_mfma_f32_16x16x32_bf16(af[i], bfr[j], acc[i][j], 0, 0, 0);
    }
    __syncthreads();
  }

#pragma unroll
  for (int j = 0; j < 4; ++j) {
    int col = tile_n * 128 + wc * 64 + j * 16 + (lane & 15);
    float bv = bias[col];
#pragma unroll
    for (int i = 0; i < 4; ++i) {
      int row0 = tile_m * 128 + wr * 64 + i * 16 + ((lane >> 4) * 4);
#pragma unroll
      for (int r = 0; r < 4; ++r) {
        C[(size_t)(row0 + r) * NT + col] = acc[i][j][r] + bv;
      }
    }
  }
}

extern "C" void kernel_launch(void* const* d_in, const int* in_sizes, int n_in,
                              void* d_out, int out_size, void* d_ws, size_t ws_size,
                              hipStream_t stream) {
  const float* x    = (const float*)d_in[0];
  const float* w4   = (const float*)d_in[1];
  const float* w8   = (const float*)d_in[2];
  const int*   perm = (const int*)d_in[3];
  const float* bias = (const float*)d_in[4];
  float*       out  = (float*)d_out;

  const size_t xb_bytes = (size_t)M_DIM * K_DIM * 2;
  const size_t wb_bytes = (size_t)NT * K_DIM * 2;

  if (ws_size >= xb_bytes + wb_bytes) {
    unsigned short* xb = (unsigned short*)d_ws;
    unsigned short* wb = xb + (size_t)M_DIM * K_DIM;
    conv_x_kernel<<<2048, 256, 0, stream>>>(x, xb, (M_DIM * K_DIM) / 8);
    conv_w_kernel<<<NT, 256, 0, stream>>>(w4, w8, perm, wb);
    gemm256_kernel<<<GRID, 512, 0, stream>>>(xb, wb, bias, out);
  } else {
    int grid = (M_DIM / 128) * (NT / 128);
    gemm_fused_f32_kernel<<<grid, 256, 0, stream>>>(x, w4, w8, perm, bias, out);
  }
}